// Round 3
// baseline (307.581 us; speedup 1.0000x reference)
//
#include <hip/hip_runtime.h>
#include <hip/hip_bf16.h>

typedef unsigned short u16;
typedef __bf16 bf16x8 __attribute__((ext_vector_type(8)));
typedef float f32x16 __attribute__((ext_vector_type(16)));

// ---------------------------------------------------------------------------
// Prep 1: x fp32 -> bf16 (RN), plus fp32 row sums. One block per row.
// ---------------------------------------------------------------------------
__device__ __forceinline__ u16 f2b(float f) {
    union { __hip_bfloat16 h; u16 u; } cv;
    cv.h = __float2bfloat16(f);
    return cv.u;
}

__global__ __launch_bounds__(256) void prep_x(const float* __restrict__ x,
                                              u16* __restrict__ xb,
                                              float* __restrict__ rowsum,
                                              int K) {
    const int row = blockIdx.x;
    const float* xr = x + (size_t)row * K;
    u16* xbr = xb + (size_t)row * K;
    float s = 0.f;
    for (int c = threadIdx.x * 4; c < K; c += blockDim.x * 4) {
        float4 v = *reinterpret_cast<const float4*>(xr + c);
        s += v.x + v.y + v.z + v.w;
        ushort4 o;
        o.x = f2b(v.x); o.y = f2b(v.y); o.z = f2b(v.z); o.w = f2b(v.w);
        *reinterpret_cast<ushort4*>(xbr + c) = o;
    }
    #pragma unroll
    for (int off = 32; off > 0; off >>= 1) s += __shfl_down(s, off);
    __shared__ float wsum[4];
    const int lane = threadIdx.x & 63, wv = threadIdx.x >> 6;
    if (lane == 0) wsum[wv] = s;
    __syncthreads();
    if (threadIdx.x == 0) rowsum[row] = wsum[0] + wsum[1] + wsum[2] + wsum[3];
}

// ---------------------------------------------------------------------------
// Prep 2: weight int32 codes (exact in bf16) -> bf16.
// ---------------------------------------------------------------------------
__global__ __launch_bounds__(256) void prep_w(const int* __restrict__ w,
                                              u16* __restrict__ wb) {
    const size_t idx = (size_t)blockIdx.x * blockDim.x + threadIdx.x;
    const size_t e = idx * 4;
    int4 v = *reinterpret_cast<const int4*>(w + e);
    ushort4 o;
    o.x = (u16)(__float_as_uint((float)v.x) >> 16);
    o.y = (u16)(__float_as_uint((float)v.y) >> 16);
    o.z = (u16)(__float_as_uint((float)v.z) >> 16);
    o.w = (u16)(__float_as_uint((float)v.w) >> 16);
    *reinterpret_cast<ushort4*>(wb + e) = o;
}

// ---------------------------------------------------------------------------
// 8-phase 256x256 GEMM (m201 template), MFMA 32x32x16, fused dequant epilogue.
// C[m,o] = scale[o]*(sum_k A[m,k]*B[o,k] - zp[o]*rowsum[m]) + bias[o]
// A: M x K bf16 row-major; B: N x K bf16 row-major (B^T GEMM).
// LDS: A halves [buf][ks][256 rows][32 k] (16 KiB each) at 0; B at +64 KiB.
// Swizzle: 16B slot within a row's 64B: slot_phys = slot_log ^ ((row>>1)&3).
// Staged linearly via global_load_lds from inverse-swizzled global source.
// ---------------------------------------------------------------------------
__device__ __forceinline__ void async16(void* lds, const void* g) {
    __builtin_amdgcn_global_load_lds(
        (const __attribute__((address_space(1))) unsigned*)g,
        (__attribute__((address_space(3))) unsigned*)lds, 16, 0, 0);
}

__global__ __launch_bounds__(512, 2) void qgemm8(
    const u16* __restrict__ A, const u16* __restrict__ B,
    const float* __restrict__ rowsum, const float* __restrict__ scale,
    const float* __restrict__ zp, const float* __restrict__ bias,
    float* __restrict__ C, int M, int N, int K) {
    extern __shared__ char smem[];
    char* const AsB = smem;            // 4 x 16 KiB A half-tiles
    char* const BsB = smem + 65536;    // 4 x 16 KiB B half-tiles

    const int tid  = threadIdx.x;
    const int lane = tid & 63;
    const int wid  = tid >> 6;
    const int wm = wid >> 2, wn = wid & 3;   // 2 x 4 waves
    const int l31 = lane & 31;
    const int hi  = lane >> 5;

    // bijective XCD swizzle (gridDim.x % 8 == 0)
    const int nbn = N >> 8;
    int wg = blockIdx.x;
    wg = (wg & 7) * (gridDim.x >> 3) + (wg >> 3);
    const int bm = wg / nbn, bn = wg % nbn;

    // per-thread staging source offsets (inverse-swizzled global address)
    const int r0s = tid >> 2, sls = tid & 3;
    size_t a_src[2], b_src[2];
    int lds_off[2];
    #pragma unroll
    for (int j = 0; j < 2; ++j) {
        const int row = r0s + j * 128;
        const int sl  = sls ^ ((row >> 1) & 3);
        a_src[j] = ((size_t)(bm * 256 + row)) * K + sl * 8;
        b_src[j] = ((size_t)(bn * 256 + row)) * K + sl * 8;
        lds_off[j] = (j * 512 + tid) * 16;
    }

    auto stageA = [&](int u, int ks, int buf) {
        const int kc = u * 64 + ks * 32;
        char* const dst = AsB + (buf * 2 + ks) * 16384;
        #pragma unroll
        for (int j = 0; j < 2; ++j) async16(dst + lds_off[j], A + a_src[j] + kc);
    };
    auto stageB = [&](int u, int ks, int buf) {
        const int kc = u * 64 + ks * 32;
        char* const dst = BsB + (buf * 2 + ks) * 16384;
        #pragma unroll
        for (int j = 0; j < 2; ++j) async16(dst + lds_off[j], B + b_src[j] + kc);
    };

    // fragment-read constants (swizzled ds_read addresses)
    // A frag (mf,kstep): row = wm*128 + mf*32 + l31; k = kstep*16 + 8*hi
    // slot_log = kstep*2 + hi; swz = (l31>>1)&3 (frag bases are mult. of 32)
    const int swz = (lane >> 1) & 3;
    int aswk[2], bswk[2];
    #pragma unroll
    for (int kst = 0; kst < 2; ++kst) {
        const int so = (((kst << 1) | hi) ^ swz) << 4;
        aswk[kst] = (wm * 128 + l31) * 64 + so;
        bswk[kst] = (wn * 64 + l31) * 64 + so;
    }

    f32x16 acc[4][2] = {};
    bf16x8 bfr[2][2];   // [nf][kstep], persists across QM phases

    const int NT  = K >> 6;    // K/64 tiles
    const int NIT = NT >> 1;   // 2 tiles / iteration

    // ---- prologue: tile0 {B0,A0,B1,A1}; tile1 {B0,A0,B1} stays in flight ----
    stageB(0, 0, 0); stageA(0, 0, 0); stageB(0, 1, 0); stageA(0, 1, 0);
    asm volatile("s_waitcnt vmcnt(4)" ::: "memory");
    stageB(1, 0, 1); stageA(1, 0, 1); stageB(1, 1, 1);
    asm volatile("s_waitcnt vmcnt(6)" ::: "memory");
    asm volatile("s_barrier" ::: "memory");

#define PHASE(BUF, KS, QM, LOADB, STAGE, WAITV)                                \
    {                                                                          \
        const char* ha = AsB + ((BUF) * 2 + (KS)) * 16384;                     \
        const char* hb = BsB + ((BUF) * 2 + (KS)) * 16384;                     \
        bf16x8 af[2][2];                                                       \
        _Pragma("unroll")                                                      \
        for (int m2 = 0; m2 < 2; ++m2)                                         \
            _Pragma("unroll")                                                  \
            for (int kst = 0; kst < 2; ++kst)                                  \
                af[m2][kst] = *(const bf16x8*)(ha + aswk[kst] +                \
                                               ((QM) * 2 + m2) * 2048);        \
        if (LOADB) {                                                           \
            _Pragma("unroll")                                                  \
            for (int n = 0; n < 2; ++n)                                        \
                _Pragma("unroll")                                              \
                for (int kst = 0; kst < 2; ++kst)                              \
                    bfr[n][kst] = *(const bf16x8*)(hb + bswk[kst] + n * 2048); \
        }                                                                      \
        STAGE;                                                                 \
        asm volatile("s_barrier" ::: "memory");                                \
        asm volatile("s_waitcnt lgkmcnt(0)" ::: "memory");                     \
        __builtin_amdgcn_sched_barrier(0);                                     \
        __builtin_amdgcn_s_setprio(1);                                         \
        _Pragma("unroll")                                                      \
        for (int kst = 0; kst < 2; ++kst) {                                    \
            _Pragma("unroll")                                                  \
            for (int m2 = 0; m2 < 2; ++m2)                                     \
                _Pragma("unroll")                                              \
                for (int n = 0; n < 2; ++n)                                    \
                    acc[(QM) * 2 + m2][n] =                                    \
                        __builtin_amdgcn_mfma_f32_32x32x16_bf16(               \
                            af[m2][kst], bfr[n][kst],                          \
                            acc[(QM) * 2 + m2][n], 0, 0, 0);                   \
        }                                                                      \
        __builtin_amdgcn_s_setprio(0);                                         \
        __builtin_amdgcn_sched_barrier(0);                                     \
        if (WAITV) asm volatile("s_waitcnt vmcnt(6)" ::: "memory");            \
        asm volatile("s_barrier" ::: "memory");                                \
    }

    #pragma unroll 1
    for (int i = 0; i < NIT; ++i) {
        const int t  = 2 * i;
        const int u1 = t + 1;
        int u2 = t + 2; if (u2 >= NT) u2 = NT - 1;   // clamped dummy prefetch
        int u3 = t + 3; if (u3 >= NT) u3 = NT - 1;   // (keeps vmcnt bookkeeping)
        PHASE(0, 0, 0, 1, stageA(u1, 1, 1), 0)   // reads t:A0,B0   | stage (t+1)A1
        PHASE(0, 0, 1, 0, stageB(u2, 0, 0), 0)   // reads t:A0     | stage (t+2)B0
        PHASE(0, 1, 0, 1, stageA(u2, 0, 0), 0)   // reads t:A1,B1  | stage (t+2)A0
        PHASE(0, 1, 1, 0, stageB(u2, 1, 0), 1)   // reads t:A1     | stage (t+2)B1 + vmcnt(6)
        PHASE(1, 0, 0, 1, stageA(u2, 1, 0), 0)   // reads t+1:A0,B0| stage (t+2)A1
        PHASE(1, 0, 1, 0, stageB(u3, 0, 1), 0)   // reads t+1:A0   | stage (t+3)B0
        PHASE(1, 1, 0, 1, stageA(u3, 0, 1), 0)   // reads t+1:A1,B1| stage (t+3)A0
        PHASE(1, 1, 1, 0, stageB(u3, 1, 1), 1)   // reads t+1:A1   | stage (t+3)B1 + vmcnt(6)
    }
#undef PHASE

    // ---- epilogue: fused dequant.
    // D (32x32): col = lane&31, row = (reg&3) + 8*(reg>>2) + 4*(lane>>5) ----
    float sc[2], zz[2], bb[2];
    #pragma unroll
    for (int n = 0; n < 2; ++n) {
        const int o = bn * 256 + wn * 64 + n * 32 + l31;
        sc[n] = scale[o]; zz[n] = zp[o]; bb[n] = bias[o];
    }
    #pragma unroll
    for (int mf = 0; mf < 4; ++mf) {
        const int rb = bm * 256 + wm * 128 + mf * 32 + hi * 4;
        #pragma unroll
        for (int g = 0; g < 4; ++g) {
            #pragma unroll
            for (int i = 0; i < 4; ++i) {
                const int row = rb + g * 8 + i;
                const float rs = rowsum[row];
                #pragma unroll
                for (int n = 0; n < 2; ++n) {
                    const int o = bn * 256 + wn * 64 + n * 32 + l31;
                    C[(size_t)row * N + o] =
                        sc[n] * (acc[mf][n][g * 4 + i] - zz[n] * rs) + bb[n];
                }
            }
        }
    }
}

// ---------------------------------------------------------------------------
extern "C" void kernel_launch(void* const* d_in, const int* in_sizes, int n_in,
                              void* d_out, int out_size, void* d_ws, size_t ws_size,
                              hipStream_t stream) {
    const float* x     = (const float*)d_in[0];
    const int*   w     = (const int*)d_in[1];
    const float* scale = (const float*)d_in[2];
    const float* zp    = (const float*)d_in[3];
    const float* bias  = (const float*)d_in[4];
    float* out = (float*)d_out;

    const int N = in_sizes[2];              // D_OUT = 4096
    const int K = in_sizes[1] / N;          // D_IN  = 4096
    const int M = in_sizes[0] / K;          // B*S   = 8192

    u16*   xb = (u16*)d_ws;
    u16*   wb = (u16*)((char*)d_ws + (size_t)M * K * 2);
    float* rs = (float*)((char*)d_ws + (size_t)M * K * 2 + (size_t)N * K * 2);

    prep_x<<<M, 256, 0, stream>>>(x, xb, rs, K);
    prep_w<<<(int)(((size_t)N * K / 4) / 256), 256, 0, stream>>>(w, wb);

    (void)hipFuncSetAttribute((const void*)qgemm8,
                              hipFuncAttributeMaxDynamicSharedMemorySize, 131072);
    const int nwg = (M / 256) * (N / 256);   // 512, % 8 == 0
    qgemm8<<<nwg, 512, 131072, stream>>>(xb, wb, rs, scale, zp, bias, out, M, N, K);
}

// Round 4
// 275.724 us; speedup vs baseline: 1.1155x; 1.1155x over previous
//
#include <hip/hip_runtime.h>
#include <hip/hip_bf16.h>

typedef unsigned short u16;
typedef __bf16 bf16x8 __attribute__((ext_vector_type(8)));
typedef float f32x4 __attribute__((ext_vector_type(4)));

// ---------------------------------------------------------------------------
// Prep 1: x fp32 -> bf16 (RN), plus fp32 row sums. One block per row.
// ---------------------------------------------------------------------------
__device__ __forceinline__ u16 f2b(float f) {
    union { __hip_bfloat16 h; u16 u; } cv;
    cv.h = __float2bfloat16(f);
    return cv.u;
}

__global__ __launch_bounds__(256) void prep_x(const float* __restrict__ x,
                                              u16* __restrict__ xb,
                                              float* __restrict__ rowsum,
                                              int K) {
    const int row = blockIdx.x;
    const float* xr = x + (size_t)row * K;
    u16* xbr = xb + (size_t)row * K;
    float s = 0.f;
    for (int c = threadIdx.x * 4; c < K; c += blockDim.x * 4) {
        float4 v = *reinterpret_cast<const float4*>(xr + c);
        s += v.x + v.y + v.z + v.w;
        ushort4 o;
        o.x = f2b(v.x); o.y = f2b(v.y); o.z = f2b(v.z); o.w = f2b(v.w);
        *reinterpret_cast<ushort4*>(xbr + c) = o;
    }
    #pragma unroll
    for (int off = 32; off > 0; off >>= 1) s += __shfl_down(s, off);
    __shared__ float wsum[4];
    const int lane = threadIdx.x & 63, wv = threadIdx.x >> 6;
    if (lane == 0) wsum[wv] = s;
    __syncthreads();
    if (threadIdx.x == 0) rowsum[row] = wsum[0] + wsum[1] + wsum[2] + wsum[3];
}

// ---------------------------------------------------------------------------
// Prep 2: weight int32 codes (exact in bf16) -> bf16.
// ---------------------------------------------------------------------------
__global__ __launch_bounds__(256) void prep_w(const int* __restrict__ w,
                                              u16* __restrict__ wb) {
    const size_t idx = (size_t)blockIdx.x * blockDim.x + threadIdx.x;
    const size_t e = idx * 4;
    int4 v = *reinterpret_cast<const int4*>(w + e);
    ushort4 o;
    o.x = (u16)(__float_as_uint((float)v.x) >> 16);
    o.y = (u16)(__float_as_uint((float)v.y) >> 16);
    o.z = (u16)(__float_as_uint((float)v.z) >> 16);
    o.w = (u16)(__float_as_uint((float)v.w) >> 16);
    *reinterpret_cast<ushort4*>(wb + e) = o;
}

// ---------------------------------------------------------------------------
// 8-phase 256x256 GEMM, counted-lgkm pipelined fragment reads (1 phase ahead),
// fused dequant epilogue.
// C[m,o] = scale[o]*(sum_k A[m,k]*B[o,k] - zp[o]*rowsum[m]) + bias[o]
// A: M x K bf16 row-major; B: N x K bf16 row-major (B^T GEMM).
// LDS: A halves [buf][ks][256 rows][32 k] (16 KiB each) at 0; B at +64 KiB.
// Swizzle: 16B slot within a row's 64B: slot_phys = slot_log ^ ((row>>1)&3).
// Staged linearly via global_load_lds from inverse-swizzled global source.
// vmcnt(8) at top of every even phase proves the stages from 5-6 phases back
// that this phase's (shifted-early) reads consume; lgkmcnt(N) = just-issued
// read count (DS retires in-order) so MFMA overlaps next phase's LDS service.
// ---------------------------------------------------------------------------
__device__ __forceinline__ void async16(void* lds, const void* g) {
    __builtin_amdgcn_global_load_lds(
        (const __attribute__((address_space(1))) unsigned*)g,
        (__attribute__((address_space(3))) unsigned*)lds, 16, 0, 0);
}

__global__ __launch_bounds__(512, 2) void qgemm8(
    const u16* __restrict__ A, const u16* __restrict__ B,
    const float* __restrict__ rowsum, const float* __restrict__ scale,
    const float* __restrict__ zp, const float* __restrict__ bias,
    float* __restrict__ C, int M, int N, int K) {
    extern __shared__ char smem[];
    char* const AsB = smem;            // 4 x 16 KiB A half-tiles
    char* const BsB = smem + 65536;    // 4 x 16 KiB B half-tiles

    const int tid  = threadIdx.x;
    const int lane = tid & 63;
    const int wid  = tid >> 6;
    const int wm = wid >> 2, wn = wid & 3;   // 2 x 4 waves
    const int l15 = lane & 15;

    // bijective XCD swizzle (gridDim.x % 8 == 0)
    const int nbn = N >> 8;
    int wg = blockIdx.x;
    wg = (wg & 7) * (gridDim.x >> 3) + (wg >> 3);
    const int bm = wg / nbn, bn = wg % nbn;

    // per-thread staging source offsets (inverse-swizzled global address)
    const int r0s = tid >> 2, sls = tid & 3;
    size_t a_src[2], b_src[2];
    int lds_off[2];
    #pragma unroll
    for (int j = 0; j < 2; ++j) {
        const int row = r0s + j * 128;
        const int sl  = sls ^ ((row >> 1) & 3);
        a_src[j] = ((size_t)(bm * 256 + row)) * K + sl * 8;
        b_src[j] = ((size_t)(bn * 256 + row)) * K + sl * 8;
        lds_off[j] = (j * 512 + tid) * 16;
    }

    auto stageA = [&](int u, int ks, int buf) {
        const int kc = u * 64 + ks * 32;
        char* const dst = AsB + (buf * 2 + ks) * 16384;
        #pragma unroll
        for (int j = 0; j < 2; ++j) async16(dst + lds_off[j], A + a_src[j] + kc);
    };
    auto stageB = [&](int u, int ks, int buf) {
        const int kc = u * 64 + ks * 32;
        char* const dst = BsB + (buf * 2 + ks) * 16384;
        #pragma unroll
        for (int j = 0; j < 2; ++j) async16(dst + lds_off[j], B + b_src[j] + kc);
    };

    // fragment-read constants (swizzled ds_read address)
    const int sw16 = (((lane >> 4) ^ ((lane >> 1) & 3)) << 4);
    const int a_ro = (wm * 128 + l15) * 64 + sw16;   // + mf*1024
    const int b_ro = (wn * 64 + l15) * 64 + sw16;    // + nf*1024

    f32x4 acc[8][4] = {};
    bf16x8 af0[4], af1[4], bfr0[4], bfr1[4];

    const int NT  = K >> 6;    // K/64 tiles
    const int NIT = NT >> 1;   // 2 tiles / iteration

#define READ_AF(DST, BUF, KS, QM)                                              \
    {                                                                          \
        const char* _ha = AsB + ((BUF) * 2 + (KS)) * 16384;                    \
        _Pragma("unroll")                                                      \
        for (int m = 0; m < 4; ++m)                                            \
            DST[m] = *(const bf16x8*)(_ha + a_ro + ((QM) * 4 + m) * 1024);     \
    }

#define READ_BF(DST, BUF, KS)                                                  \
    {                                                                          \
        const char* _hb = BsB + ((BUF) * 2 + (KS)) * 16384;                    \
        _Pragma("unroll")                                                      \
        for (int n = 0; n < 4; ++n)                                            \
            DST[n] = *(const bf16x8*)(_hb + b_ro + n * 1024);                  \
    }

#define MFMA16(QM, AF, BF)                                                     \
    __builtin_amdgcn_s_setprio(1);                                             \
    _Pragma("unroll")                                                          \
    for (int m = 0; m < 4; ++m)                                                \
        _Pragma("unroll")                                                      \
        for (int n = 0; n < 4; ++n)                                            \
            acc[(QM) * 4 + m][n] = __builtin_amdgcn_mfma_f32_16x16x32_bf16(    \
                AF[m], BF[n], acc[(QM) * 4 + m][n], 0, 0, 0);                  \
    __builtin_amdgcn_s_setprio(0);

#define LGKM(N) asm volatile("s_waitcnt lgkmcnt(" #N ")" ::: "memory");        \
                __builtin_amdgcn_sched_barrier(0);
#define ENDPH   __builtin_amdgcn_sched_barrier(0);                             \
                asm volatile("s_barrier" ::: "memory");
#define VM8     asm volatile("s_waitcnt vmcnt(8)" ::: "memory");

    // ---- prologue: tile0 {B0,A0,B1,A1}; tile1 {B0,A0,B1} stays in flight ----
    stageB(0, 0, 0); stageA(0, 0, 0); stageB(0, 1, 0); stageA(0, 1, 0);
    asm volatile("s_waitcnt vmcnt(4)" ::: "memory");
    stageB(1, 0, 1); stageA(1, 0, 1); stageB(1, 1, 1);
    asm volatile("s_waitcnt vmcnt(6)" ::: "memory");
    asm volatile("s_barrier" ::: "memory");
    // R(1): tile0 KS0 QM0 fragments + B fragments
    READ_AF(af1, 0, 0, 0);
    READ_BF(bfr0, 0, 0);

    #pragma unroll 1
    for (int i = 0; i < NIT; ++i) {
        const int t  = 2 * i;
        const int u1 = t + 1;
        int u2 = t + 2; if (u2 >= NT) u2 = NT - 1;   // clamped dummy prefetch
        int u3 = t + 3; if (u3 >= NT) u3 = NT - 1;   // (keeps vmcnt bookkeeping)

        // ph1: MFMA t:KS0:QM0 | prefetch R2 (t:KS0 QM1 af) | stage A(t+1,1)
        READ_AF(af0, 0, 0, 1);
        stageA(u1, 1, 1);
        LGKM(4)
        MFMA16(0, af1, bfr0);
        ENDPH
        // ph2: MFMA t:KS0:QM1 | prefetch R3 (t:KS1 af+bf) | stage B(t+2,0)
        VM8
        READ_AF(af1, 0, 1, 0);
        READ_BF(bfr1, 0, 1);
        stageB(u2, 0, 0);
        LGKM(8)
        MFMA16(1, af0, bfr0);
        ENDPH
        // ph3: MFMA t:KS1:QM0 | prefetch R4 (t:KS1 QM1 af) | stage A(t+2,0)
        READ_AF(af0, 0, 1, 1);
        stageA(u2, 0, 0);
        LGKM(4)
        MFMA16(0, af1, bfr1);
        ENDPH
        // ph4: MFMA t:KS1:QM1 | prefetch R5 (t+1:KS0 af+bf) | stage B(t+2,1)
        VM8
        READ_AF(af1, 1, 0, 0);
        READ_BF(bfr0, 1, 0);
        stageB(u2, 1, 0);
        LGKM(8)
        MFMA16(1, af0, bfr1);
        ENDPH
        // ph5: MFMA t+1:KS0:QM0 | prefetch R6 (t+1:KS0 QM1 af) | stage A(t+2,1)
        READ_AF(af0, 1, 0, 1);
        stageA(u2, 1, 0);
        LGKM(4)
        MFMA16(0, af1, bfr0);
        ENDPH
        // ph6: MFMA t+1:KS0:QM1 | prefetch R7 (t+1:KS1 af+bf) | stage B(t+3,0)
        VM8
        READ_AF(af1, 1, 1, 0);
        READ_BF(bfr1, 1, 1);
        stageB(u3, 0, 1);
        LGKM(8)
        MFMA16(1, af0, bfr0);
        ENDPH
        // ph7: MFMA t+1:KS1:QM0 | prefetch R8 (t+1:KS1 QM1 af) | stage A(t+3,0)
        READ_AF(af0, 1, 1, 1);
        stageA(u3, 0, 1);
        LGKM(4)
        MFMA16(0, af1, bfr1);
        ENDPH
        // ph8: MFMA t+1:KS1:QM1 | prefetch R1' (t+2:KS0 af+bf) | stage B(t+3,1)
        VM8
        READ_AF(af1, 0, 0, 0);
        READ_BF(bfr0, 0, 0);
        stageB(u3, 1, 1);
        LGKM(8)
        MFMA16(1, af0, bfr1);
        ENDPH
    }
#undef READ_AF
#undef READ_BF
#undef MFMA16
#undef LGKM
#undef ENDPH
#undef VM8

    // ---- epilogue: fused dequant. D: col=lane&15, row=4*(lane>>4)+i ----
    float sc[4], zz[4], bb[4];
    #pragma unroll
    for (int n = 0; n < 4; ++n) {
        const int o = bn * 256 + wn * 64 + n * 16 + l15;
        sc[n] = scale[o]; zz[n] = zp[o]; bb[n] = bias[o];
    }
    const int hi4 = (lane >> 4) << 2;
    #pragma unroll
    for (int mf = 0; mf < 8; ++mf) {
        const int r0 = bm * 256 + wm * 128 + mf * 16 + hi4;
        float rs[4];
        #pragma unroll
        for (int i = 0; i < 4; ++i) rs[i] = rowsum[r0 + i];
        #pragma unroll
        for (int n = 0; n < 4; ++n) {
            const int o = bn * 256 + wn * 64 + n * 16 + l15;
            #pragma unroll
            for (int i = 0; i < 4; ++i)
                C[(size_t)(r0 + i) * N + o] =
                    sc[n] * (acc[mf][n][i] - zz[n] * rs[i]) + bb[n];
        }
    }
}

// ---------------------------------------------------------------------------
extern "C" void kernel_launch(void* const* d_in, const int* in_sizes, int n_in,
                              void* d_out, int out_size, void* d_ws, size_t ws_size,
                              hipStream_t stream) {
    const float* x     = (const float*)d_in[0];
    const int*   w     = (const int*)d_in[1];
    const float* scale = (const float*)d_in[2];
    const float* zp    = (const float*)d_in[3];
    const float* bias  = (const float*)d_in[4];
    float* out = (float*)d_out;

    const int N = in_sizes[2];              // D_OUT = 4096
    const int K = in_sizes[1] / N;          // D_IN  = 4096
    const int M = in_sizes[0] / K;          // B*S   = 8192

    u16*   xb = (u16*)d_ws;
    u16*   wb = (u16*)((char*)d_ws + (size_t)M * K * 2);
    float* rs = (float*)((char*)d_ws + (size_t)M * K * 2 + (size_t)N * K * 2);

    prep_x<<<M, 256, 0, stream>>>(x, xb, rs, K);
    prep_w<<<(int)(((size_t)N * K / 4) / 256), 256, 0, stream>>>(w, wb);

    (void)hipFuncSetAttribute((const void*)qgemm8,
                              hipFuncAttributeMaxDynamicSharedMemorySize, 131072);
    const int nwg = (M / 256) * (N / 256);   // 512, % 8 == 0
    qgemm8<<<nwg, 512, 131072, stream>>>(xb, wb, rs, scale, zp, bias, out, M, N, K);
}

// Round 5
// 181.841 us; speedup vs baseline: 1.6915x; 1.5163x over previous
//
#include <hip/hip_runtime.h>
#include <hip/hip_bf16.h>

typedef int  i32x4 __attribute__((ext_vector_type(4)));

// ---------------------------------------------------------------------------
// Prep 1: x fp32 -> int8 (per-row symmetric quant), int rowsum folded to fp32.
// One block per row; row staged in LDS for the two-pass (max, then quantize).
// xq packed 4 codes / int32 word.
// ---------------------------------------------------------------------------
__global__ __launch_bounds__(256) void prep_x_i8(const float* __restrict__ x,
                                                 int* __restrict__ xq,
                                                 float* __restrict__ rsum,
                                                 float* __restrict__ rscale,
                                                 int K) {
    const int row = blockIdx.x;
    const float* xr = x + (size_t)row * K;
    __shared__ float xs[4096];
    float mx = 0.f;
    for (int c = threadIdx.x * 4; c < K; c += blockDim.x * 4) {
        float4 v = *reinterpret_cast<const float4*>(xr + c);
        *reinterpret_cast<float4*>(xs + c) = v;
        mx = fmaxf(mx, fmaxf(fmaxf(fabsf(v.x), fabsf(v.y)),
                             fmaxf(fabsf(v.z), fabsf(v.w))));
    }
    #pragma unroll
    for (int off = 32; off > 0; off >>= 1) mx = fmaxf(mx, __shfl_down(mx, off));
    __shared__ float wmax[4];
    __shared__ float s_sx, s_inv;
    const int lane = threadIdx.x & 63, wv = threadIdx.x >> 6;
    if (lane == 0) wmax[wv] = mx;
    __syncthreads();
    if (threadIdx.x == 0) {
        float m = fmaxf(fmaxf(wmax[0], wmax[1]), fmaxf(wmax[2], wmax[3]));
        m = fmaxf(m, 1e-20f);
        s_sx = m / 127.f; s_inv = 127.f / m;
    }
    __syncthreads();
    const float inv = s_inv;
    int qs = 0;
    for (int c = threadIdx.x * 4; c < K; c += blockDim.x * 4) {
        float4 v = *reinterpret_cast<const float4*>(xs + c);
        const int q0 = __float2int_rn(v.x * inv), q1 = __float2int_rn(v.y * inv);
        const int q2 = __float2int_rn(v.z * inv), q3 = __float2int_rn(v.w * inv);
        qs += q0 + q1 + q2 + q3;
        const unsigned p = (unsigned)(q0 & 255) | ((unsigned)(q1 & 255) << 8) |
                           ((unsigned)(q2 & 255) << 16) | ((unsigned)(q3 & 255) << 24);
        xq[((size_t)row * K + c) >> 2] = (int)p;
    }
    #pragma unroll
    for (int off = 32; off > 0; off >>= 1) qs += __shfl_down(qs, off);
    __shared__ int wqs[4];
    if (lane == 0) wqs[wv] = qs;
    __syncthreads();
    if (threadIdx.x == 0) {
        const int t = wqs[0] + wqs[1] + wqs[2] + wqs[3];
        rsum[row] = s_sx * (float)t;
        rscale[row] = s_sx;
    }
}

// ---------------------------------------------------------------------------
// Prep 2: weight int32 codes -> int8 bytes. 16 codes / thread, 16B writes.
// ---------------------------------------------------------------------------
__global__ __launch_bounds__(256) void prep_w_i8(const int* __restrict__ w,
                                                 int* __restrict__ wq) {
    const size_t i = (size_t)blockIdx.x * blockDim.x + threadIdx.x;
    const int4* src = reinterpret_cast<const int4*>(w) + i * 4;
    int4 a = src[0], b = src[1], c = src[2], d = src[3];
    int4 o;
    o.x = (a.x & 255) | ((a.y & 255) << 8) | ((a.z & 255) << 16) | ((a.w & 255) << 24);
    o.y = (b.x & 255) | ((b.y & 255) << 8) | ((b.z & 255) << 16) | ((b.w & 255) << 24);
    o.z = (c.x & 255) | ((c.y & 255) << 8) | ((c.z & 255) << 16) | ((c.w & 255) << 24);
    o.w = (d.x & 255) | ((d.y & 255) << 8) | ((d.z & 255) << 16) | ((d.w & 255) << 24);
    reinterpret_cast<int4*>(wq)[i] = o;
}

// ---------------------------------------------------------------------------
// 8-phase 256x256 int8 GEMM (same byte-geometry as the verified bf16 m201
// port; counted-lgkm fragment pipeline from R3). MFMA i32_16x16x64_i8.
// out[m,o] = sc[o]*(sx[m]*dot_i32[m,o] - zp[o]*rsum[m]) + bias[o]
// A: M x K i8 row-major; B: N x K i8 row-major (B^T GEMM).
// LDS unit = 256 rows x 64 B (one K=64 slab) = 16 KiB; 4 A units + 4 B units.
// Tile BK=128 = 2 units (ks); double-buffered (buf). Swizzle: 16B slot within
// a row's 64B: phys = log ^ ((row>>1)&3); staged linearly via global_load_lds
// from inverse-swizzled global source. vmcnt(8) at even phases; lgkmcnt(N) =
// just-issued ds_read count so MFMA overlaps next phase's LDS service.
// ---------------------------------------------------------------------------
__device__ __forceinline__ void async16(void* lds, const void* g) {
    __builtin_amdgcn_global_load_lds(
        (const __attribute__((address_space(1))) unsigned*)g,
        (__attribute__((address_space(3))) unsigned*)lds, 16, 0, 0);
}

__global__ __launch_bounds__(512, 2) void qgemm8i(
    const char* __restrict__ A, const char* __restrict__ B,
    const float* __restrict__ rsum, const float* __restrict__ rscale,
    const float* __restrict__ scale, const float* __restrict__ zp,
    const float* __restrict__ bias, float* __restrict__ C,
    int M, int N, int K) {
    extern __shared__ char smem[];
    char* const AsB = smem;            // 4 x 16 KiB A units
    char* const BsB = smem + 65536;    // 4 x 16 KiB B units

    const int tid  = threadIdx.x;
    const int lane = tid & 63;
    const int wid  = tid >> 6;
    const int wm = wid >> 2, wn = wid & 3;   // 2 x 4 waves
    const int l15 = lane & 15;

    // bijective XCD swizzle (gridDim.x % 8 == 0)
    const int nbn = N >> 8;
    int wg = blockIdx.x;
    wg = (wg & 7) * (gridDim.x >> 3) + (wg >> 3);
    const int bm = wg / nbn, bn = wg % nbn;

    // per-thread staging source offsets (inverse-swizzled global address)
    const int r0s = tid >> 2, sls = tid & 3;
    size_t a_src[2], b_src[2];
    int lds_off[2];
    #pragma unroll
    for (int j = 0; j < 2; ++j) {
        const int row = r0s + j * 128;
        const int sl  = sls ^ ((row >> 1) & 3);
        a_src[j] = ((size_t)(bm * 256 + row)) * K + sl * 16;
        b_src[j] = ((size_t)(bn * 256 + row)) * K + sl * 16;
        lds_off[j] = (j * 512 + tid) * 16;
    }

    auto stageA = [&](int u, int ks, int buf) {
        const int kc = u * 128 + ks * 64;     // byte offset along K
        char* const dst = AsB + (buf * 2 + ks) * 16384;
        #pragma unroll
        for (int j = 0; j < 2; ++j) async16(dst + lds_off[j], A + a_src[j] + kc);
    };
    auto stageB = [&](int u, int ks, int buf) {
        const int kc = u * 128 + ks * 64;
        char* const dst = BsB + (buf * 2 + ks) * 16384;
        #pragma unroll
        for (int j = 0; j < 2; ++j) async16(dst + lds_off[j], B + b_src[j] + kc);
    };

    // fragment-read constants (swizzled ds_read address)
    // frag: row = base + l15; 16 B at k-slot (lane>>4): k = 16*(l>>4)+i
    const int sw16 = (((lane >> 4) ^ ((lane >> 1) & 3)) << 4);
    const int a_ro = (wm * 128 + l15) * 64 + sw16;   // + mf*1024
    const int b_ro = (wn * 64 + l15) * 64 + sw16;    // + nf*1024

    i32x4 acc[8][4] = {};
    i32x4 af0[4], af1[4], bfr0[4], bfr1[4];

    const int NT  = K >> 7;    // K/128 tiles = 32
    const int NIT = NT >> 1;   // 2 tiles / iteration

#define READ_AF(DST, BUF, KS, QM)                                              \
    {                                                                          \
        const char* _ha = AsB + ((BUF) * 2 + (KS)) * 16384;                    \
        _Pragma("unroll")                                                      \
        for (int m = 0; m < 4; ++m)                                            \
            DST[m] = *(const i32x4*)(_ha + a_ro + ((QM) * 4 + m) * 1024);      \
    }

#define READ_BF(DST, BUF, KS)                                                  \
    {                                                                          \
        const char* _hb = BsB + ((BUF) * 2 + (KS)) * 16384;                    \
        _Pragma("unroll")                                                      \
        for (int n = 0; n < 4; ++n)                                            \
            DST[n] = *(const i32x4*)(_hb + b_ro + n * 1024);                   \
    }

#define MFMA16(QM, AF, BF)                                                     \
    __builtin_amdgcn_s_setprio(1);                                             \
    _Pragma("unroll")                                                          \
    for (int m = 0; m < 4; ++m)                                                \
        _Pragma("unroll")                                                      \
        for (int n = 0; n < 4; ++n)                                            \
            acc[(QM) * 4 + m][n] = __builtin_amdgcn_mfma_i32_16x16x64_i8(      \
                AF[m], BF[n], acc[(QM) * 4 + m][n], 0, 0, 0);                  \
    __builtin_amdgcn_s_setprio(0);

#define LGKM(N) asm volatile("s_waitcnt lgkmcnt(" #N ")" ::: "memory");        \
                __builtin_amdgcn_sched_barrier(0);
#define ENDPH   __builtin_amdgcn_sched_barrier(0);                             \
                asm volatile("s_barrier" ::: "memory");
#define VM8     asm volatile("s_waitcnt vmcnt(8)" ::: "memory");

    // ---- prologue: tile0 {B0,A0,B1,A1}; tile1 {B0,A0,B1} stays in flight ----
    stageB(0, 0, 0); stageA(0, 0, 0); stageB(0, 1, 0); stageA(0, 1, 0);
    asm volatile("s_waitcnt vmcnt(4)" ::: "memory");
    stageB(1, 0, 1); stageA(1, 0, 1); stageB(1, 1, 1);
    asm volatile("s_waitcnt vmcnt(6)" ::: "memory");
    asm volatile("s_barrier" ::: "memory");
    READ_AF(af1, 0, 0, 0);
    READ_BF(bfr0, 0, 0);

    #pragma unroll 1
    for (int i = 0; i < NIT; ++i) {
        const int t  = 2 * i;
        const int u1 = t + 1;
        int u2 = t + 2; if (u2 >= NT) u2 = NT - 1;   // clamped dummy prefetch
        int u3 = t + 3; if (u3 >= NT) u3 = NT - 1;   // (keeps vmcnt bookkeeping)

        // ph1: MFMA t:KS0:QM0 | prefetch (t:KS0 QM1 af) | stage A(t+1,1)
        READ_AF(af0, 0, 0, 1);
        stageA(u1, 1, 1);
        LGKM(4)
        MFMA16(0, af1, bfr0);
        ENDPH
        // ph2: MFMA t:KS0:QM1 | prefetch (t:KS1 af+bf) | stage B(t+2,0)
        VM8
        READ_AF(af1, 0, 1, 0);
        READ_BF(bfr1, 0, 1);
        stageB(u2, 0, 0);
        LGKM(8)
        MFMA16(1, af0, bfr0);
        ENDPH
        // ph3: MFMA t:KS1:QM0 | prefetch (t:KS1 QM1 af) | stage A(t+2,0)
        READ_AF(af0, 0, 1, 1);
        stageA(u2, 0, 0);
        LGKM(4)
        MFMA16(0, af1, bfr1);
        ENDPH
        // ph4: MFMA t:KS1:QM1 | prefetch (t+1:KS0 af+bf) | stage B(t+2,1)
        VM8
        READ_AF(af1, 1, 0, 0);
        READ_BF(bfr0, 1, 0);
        stageB(u2, 1, 0);
        LGKM(8)
        MFMA16(1, af0, bfr1);
        ENDPH
        // ph5: MFMA t+1:KS0:QM0 | prefetch (t+1:KS0 QM1 af) | stage A(t+2,1)
        READ_AF(af0, 1, 0, 1);
        stageA(u2, 1, 0);
        LGKM(4)
        MFMA16(0, af1, bfr0);
        ENDPH
        // ph6: MFMA t+1:KS0:QM1 | prefetch (t+1:KS1 af+bf) | stage B(t+3,0)
        VM8
        READ_AF(af1, 1, 1, 0);
        READ_BF(bfr1, 1, 1);
        stageB(u3, 0, 1);
        LGKM(8)
        MFMA16(1, af0, bfr0);
        ENDPH
        // ph7: MFMA t+1:KS1:QM0 | prefetch (t+1:KS1 QM1 af) | stage A(t+3,0)
        READ_AF(af0, 1, 1, 1);
        stageA(u3, 0, 1);
        LGKM(4)
        MFMA16(0, af1, bfr1);
        ENDPH
        // ph8: MFMA t+1:KS1:QM1 | prefetch (t+2:KS0 af+bf) | stage B(t+3,1)
        VM8
        READ_AF(af1, 0, 0, 0);
        READ_BF(bfr0, 0, 0);
        stageB(u3, 1, 1);
        LGKM(8)
        MFMA16(1, af0, bfr1);
        ENDPH
    }
#undef READ_AF
#undef READ_BF
#undef MFMA16
#undef LGKM
#undef ENDPH
#undef VM8

    // ---- epilogue: dequant. D: col=lane&15, row=4*(lane>>4)+i ----
    float sc[4], zz[4], bb[4];
    #pragma unroll
    for (int n = 0; n < 4; ++n) {
        const int o = bn * 256 + wn * 64 + n * 16 + l15;
        sc[n] = scale[o]; zz[n] = zp[o]; bb[n] = bias[o];
    }
    const int hi4 = (lane >> 4) << 2;
    #pragma unroll
    for (int mf = 0; mf < 8; ++mf) {
        const int r0 = bm * 256 + wm * 128 + mf * 16 + hi4;
        float rs[4], sx[4];
        #pragma unroll
        for (int i = 0; i < 4; ++i) { rs[i] = rsum[r0 + i]; sx[i] = rscale[r0 + i]; }
        #pragma unroll
        for (int n = 0; n < 4; ++n) {
            const int o = bn * 256 + wn * 64 + n * 16 + l15;
            #pragma unroll
            for (int i = 0; i < 4; ++i)
                C[(size_t)(r0 + i) * N + o] =
                    sc[n] * (sx[i] * (float)acc[mf][n][i] - zz[n] * rs[i]) + bb[n];
        }
    }
}

// ---------------------------------------------------------------------------
extern "C" void kernel_launch(void* const* d_in, const int* in_sizes, int n_in,
                              void* d_out, int out_size, void* d_ws, size_t ws_size,
                              hipStream_t stream) {
    const float* x     = (const float*)d_in[0];
    const int*   w     = (const int*)d_in[1];
    const float* scale = (const float*)d_in[2];
    const float* zp    = (const float*)d_in[3];
    const float* bias  = (const float*)d_in[4];
    float* out = (float*)d_out;

    const int N = in_sizes[2];              // D_OUT = 4096
    const int K = in_sizes[1] / N;          // D_IN  = 4096
    const int M = in_sizes[0] / K;          // B*S   = 8192

    char*  xq  = (char*)d_ws;                                   // M*K bytes
    char*  wq  = (char*)d_ws + (size_t)M * K;                   // N*K bytes
    float* rs  = (float*)((char*)d_ws + (size_t)M * K + (size_t)N * K);
    float* rsc = rs + M;

    prep_x_i8<<<M, 256, 0, stream>>>(x, (int*)xq, rs, rsc, K);
    prep_w_i8<<<(int)(((size_t)N * K / 16) / 256), 256, 0, stream>>>(w, (int*)wq);

    (void)hipFuncSetAttribute((const void*)qgemm8i,
                              hipFuncAttributeMaxDynamicSharedMemorySize, 131072);
    const int nwg = (M / 256) * (N / 256);   // 512, % 8 == 0
    qgemm8i<<<nwg, 512, 131072, stream>>>(xq, wq, rs, rsc, scale, zp, bias,
                                          out, M, N, K);
}